// Round 7
// baseline (463.983 us; speedup 1.0000x reference)
//
#include <hip/hip_runtime.h>
#include <math.h>

#define N_NODES 2048
#define N_EDGES 65536
#define SEQL 5
#define IN_F 32
#define HID 64
#define OUT_F 16
#define LN_EPS 1e-5f
#define CAP 128   // fixed slot capacity per node; in-degree ~ Poisson(32), P(>128) ~ e^-200
#define NBLK 512
#define PSTR 36   // padded part row stride (floats): slot stride 180 % 32 = 20 -> banks spread

// Grid barrier: arrivals spread over 16 counters (32 RMWs each), polling via relaxed LOADS
// (no RMW serialization -- the R5 mega's 282us pathology was atomicAdd(bar,0) polling).
// Co-residency: __launch_bounds__(512,4) forces VGPR<=128 -> 4 waves/SIMD -> 2 blocks/CU
// (=512 blocks); LDS 33.8KB -> 4/CU. 2/CU is guaranteed, so all 512 blocks are resident.
__device__ __forceinline__ void gbar(unsigned* bar, unsigned target, int blk){
    __syncthreads();
    if (threadIdx.x == 0){
        __threadfence();                         // release
        __hip_atomic_fetch_add(&bar[blk & 15], 1u, __ATOMIC_RELAXED, __HIP_MEMORY_SCOPE_AGENT);
        unsigned s;
        do {
            __builtin_amdgcn_s_sleep(8);
            s = 0;
            #pragma unroll
            for (int i = 0; i < 16; ++i)
                s += __hip_atomic_load(&bar[i], __ATOMIC_RELAXED, __HIP_MEMORY_SCOPE_AGENT);
        } while (s < target);
        __threadfence();                         // acquire
    }
    __syncthreads();
}

union SMem {
    struct { float part[40*SEQL*PSTR]; } ga;                              // 28.8 KB
    struct { float wl[4096], axsf[8*160], hsf[8*320], hembf[8*64]; } de;  // 33.8 KB
    struct { float bs[64*65], wv[64]; } sc;                               // 16.9 KB
};

// ---- score tile: 32 rows x 64 cols, 8 waves x 4 rows (R4-proven 512-thread shape) ----
__device__ __forceinline__ void score_tile(int tl, int tid, SMem& sm,
        const float* __restrict__ ag, const float* __restrict__ bjp,
        const float* __restrict__ Wi2, const float* __restrict__ bi2,
        float* __restrict__ outs){
    int j0 = (tl & 31) * 64;
    int i0 = (tl >> 5) * 32;
    __syncthreads();                             // previous smem users done
    for (int idx = tid; idx < 4096; idx += 512){
        int jj = idx >> 6, f = idx & 63;
        sm.sc.bs[jj*65 + f] = bjp[(j0 + jj)*HID + f];
    }
    if (tid < 64) sm.sc.wv[tid] = Wi2[tid];
    __syncthreads();
    int tj = tid & 63;
    int w = __builtin_amdgcn_readfirstlane(tid >> 6);   // wave-uniform -> scalar a-loads
    const float* ar = ag + (i0 + w*4)*HID;
    float bi2v = bi2[0];
    float acc0 = 0.f, acc1 = 0.f, acc2 = 0.f, acc3 = 0.f;
    #pragma unroll
    for (int f = 0; f < 64; ++f){
        float bv = sm.sc.bs[tj*65 + f];
        float wf = sm.sc.wv[f];
        acc0 += fmaxf(ar[       f] + bv, 0.f) * wf;
        acc1 += fmaxf(ar[ 64 +  f] + bv, 0.f) * wf;
        acc2 += fmaxf(ar[128 +  f] + bv, 0.f) * wf;
        acc3 += fmaxf(ar[192 +  f] + bv, 0.f) * wf;
    }
    long ro = (long)(i0 + w*4) * N_NODES + j0 + tj;
    outs[ro                ] = acc0 + bi2v;
    outs[ro +     N_NODES  ] = acc1 + bi2v;
    outs[ro + 2L* N_NODES  ] = acc2 + bi2v;
    outs[ro + 3L* N_NODES  ] = acc3 + bi2v;
}

// ---- gcn layers, wave-per-node (verbatim R6) ----
__device__ __forceinline__ void gcn1_node(int n, int l,
        const float* __restrict__ deg, const int* __restrict__ cnt,
        const float2* __restrict__ cedge, const float* __restrict__ hw1y,
        const float* __restrict__ bc1, const float* __restrict__ g1,
        const float* __restrict__ be1, const float* __restrict__ Wc2,
        float* __restrict__ hw2y){
    int slot = l >> 4, fl = l & 15;
    int m = min(cnt[n], CAP);
    float dv = 1.f / sqrtf(deg[n] + 1.f);
    const float4* H4 = (const float4*)hw1y;
    float4 acc = {0.f,0.f,0.f,0.f};
    if (slot == 0) acc = H4[n*16 + fl];          // self term (hw1y pre-scaled by dinv[n])
    for (int p = slot; p < m; p += 4){
        float2 ed = cedge[(n << 7) + p];
        int s = __float_as_int(ed.x); float c = ed.y;
        float4 h = H4[s*16 + fl];
        acc.x += c*h.x; acc.y += c*h.y; acc.z += c*h.z; acc.w += c*h.w;
    }
    acc.x += __shfl_xor(acc.x, 16); acc.y += __shfl_xor(acc.y, 16);
    acc.z += __shfl_xor(acc.z, 16); acc.w += __shfl_xor(acc.w, 16);
    acc.x += __shfl_xor(acc.x, 32); acc.y += __shfl_xor(acc.y, 32);
    acc.z += __shfl_xor(acc.z, 32); acc.w += __shfl_xor(acc.w, 32);
    float4 b4 = ((const float4*)bc1)[fl];
    float4 g;
    g.x = b4.x + dv*acc.x; g.y = b4.y + dv*acc.y;
    g.z = b4.z + dv*acc.z; g.w = b4.w + dv*acc.w;
    float s4 = g.x + g.y + g.z + g.w;
    s4 += __shfl_xor(s4, 1); s4 += __shfl_xor(s4, 2);
    s4 += __shfl_xor(s4, 4); s4 += __shfl_xor(s4, 8);
    float mu = s4 * (1.f/64.f);
    float4 d;
    d.x = g.x - mu; d.y = g.y - mu; d.z = g.z - mu; d.w = g.w - mu;
    float v4 = d.x*d.x + d.y*d.y + d.z*d.z + d.w*d.w;
    v4 += __shfl_xor(v4, 1); v4 += __shfl_xor(v4, 2);
    v4 += __shfl_xor(v4, 4); v4 += __shfl_xor(v4, 8);
    float rs = 1.f / sqrtf(v4 * (1.f/64.f) + LN_EPS);
    float4 gm = ((const float4*)g1)[fl], be = ((const float4*)be1)[fl];
    float4 h4;
    h4.x = fmaxf(d.x*rs*gm.x + be.x, 0.f);
    h4.y = fmaxf(d.y*rs*gm.y + be.y, 0.f);
    h4.z = fmaxf(d.z*rs*gm.z + be.z, 0.f);
    h4.w = fmaxf(d.w*rs*gm.w + be.w, 0.f);
    float o = 0.f;
    #pragma unroll 4
    for (int gk = 0; gk < 16; ++gk){
        float hb0 = __shfl(h4.x, gk);
        float hb1 = __shfl(h4.y, gk);
        float hb2 = __shfl(h4.z, gk);
        float hb3 = __shfl(h4.w, gk);
        o += hb0 * Wc2[(4*gk+0)*HID + l];
        o += hb1 * Wc2[(4*gk+1)*HID + l];
        o += hb2 * Wc2[(4*gk+2)*HID + l];
        o += hb3 * Wc2[(4*gk+3)*HID + l];
    }
    hw2y[n*HID + l] = dv * o;                    // pre-scale for gcn2 gather
}

__device__ __forceinline__ void gcn2_node(int n, int l,
        const float* __restrict__ deg, const int* __restrict__ cnt,
        const float2* __restrict__ cedge, const float* __restrict__ hw2y,
        const float* __restrict__ bc2, const float* __restrict__ g2,
        const float* __restrict__ be2, const float* __restrict__ Wout,
        const float* __restrict__ bout, float* __restrict__ outp){
    int slot = l >> 4, fl = l & 15;
    int m = min(cnt[n], CAP);
    float dv = 1.f / sqrtf(deg[n] + 1.f);
    const float4* H4 = (const float4*)hw2y;
    float4 acc = {0.f,0.f,0.f,0.f};
    if (slot == 0) acc = H4[n*16 + fl];
    for (int p = slot; p < m; p += 4){
        float2 ed = cedge[(n << 7) + p];
        int s = __float_as_int(ed.x); float c = ed.y;
        float4 h = H4[s*16 + fl];
        acc.x += c*h.x; acc.y += c*h.y; acc.z += c*h.z; acc.w += c*h.w;
    }
    acc.x += __shfl_xor(acc.x, 16); acc.y += __shfl_xor(acc.y, 16);
    acc.z += __shfl_xor(acc.z, 16); acc.w += __shfl_xor(acc.w, 16);
    acc.x += __shfl_xor(acc.x, 32); acc.y += __shfl_xor(acc.y, 32);
    acc.z += __shfl_xor(acc.z, 32); acc.w += __shfl_xor(acc.w, 32);
    float4 b4 = ((const float4*)bc2)[fl];
    float4 g;
    g.x = b4.x + dv*acc.x; g.y = b4.y + dv*acc.y;
    g.z = b4.z + dv*acc.z; g.w = b4.w + dv*acc.w;
    float s4 = g.x + g.y + g.z + g.w;
    s4 += __shfl_xor(s4, 1); s4 += __shfl_xor(s4, 2);
    s4 += __shfl_xor(s4, 4); s4 += __shfl_xor(s4, 8);
    float mu = s4 * (1.f/64.f);
    float4 d;
    d.x = g.x - mu; d.y = g.y - mu; d.z = g.z - mu; d.w = g.w - mu;
    float v4 = d.x*d.x + d.y*d.y + d.z*d.z + d.w*d.w;
    v4 += __shfl_xor(v4, 1); v4 += __shfl_xor(v4, 2);
    v4 += __shfl_xor(v4, 4); v4 += __shfl_xor(v4, 8);
    float rs = 1.f / sqrtf(v4 * (1.f/64.f) + LN_EPS);
    float4 gm = ((const float4*)g2)[fl], be = ((const float4*)be2)[fl];
    float4 h4;
    h4.x = fmaxf(d.x*rs*gm.x + be.x, 0.f);
    h4.y = fmaxf(d.y*rs*gm.y + be.y, 0.f);
    h4.z = fmaxf(d.z*rs*gm.z + be.z, 0.f);
    h4.w = fmaxf(d.w*rs*gm.w + be.w, 0.f);
    int f2 = l & 15;
    float o = bout[f2];
    #pragma unroll 4
    for (int gk = 0; gk < 16; ++gk){
        float hb0 = __shfl(h4.x, gk);
        float hb1 = __shfl(h4.y, gk);
        float hb2 = __shfl(h4.z, gk);
        float hb3 = __shfl(h4.w, gk);
        o += hb0 * Wout[(4*gk+0)*OUT_F + f2];
        o += hb1 * Wout[(4*gk+1)*OUT_F + f2];
        o += hb2 * Wout[(4*gk+2)*OUT_F + f2];
        o += hb3 * Wout[(4*gk+3)*OUT_F + f2];
    }
    if (slot == 0) outp[n*OUT_F + f2] = o;
}

// ===================== mega v2: 512 blocks x 512 threads, 2 blocks/CU =====================
__global__ __launch_bounds__(512, 4) void k_mega(
        const float* __restrict__ x, const float* __restrict__ ew, const int* __restrict__ ei,
        const float* __restrict__ Wcz, const float* __restrict__ Wlz,
        const float* __restrict__ bcz, const float* __restrict__ blz,
        const float* __restrict__ Wch, const float* __restrict__ Wlh,
        const float* __restrict__ bch, const float* __restrict__ blh,
        const float* __restrict__ Wred, const float* __restrict__ bred,
        const float* __restrict__ Wc1, const float* __restrict__ bc1,
        const float* __restrict__ Wc2, const float* __restrict__ bc2,
        const float* __restrict__ g1, const float* __restrict__ be1,
        const float* __restrict__ g2, const float* __restrict__ be2,
        const float* __restrict__ Wout, const float* __restrict__ bout,
        const float* __restrict__ Wi1, const float* __restrict__ bi1,
        const float* __restrict__ Wi2, const float* __restrict__ bi2,
        float* __restrict__ deg, int* __restrict__ cnt, unsigned* __restrict__ bar,
        float2* __restrict__ cedge,
        float* __restrict__ Wzp, float* __restrict__ Whp, float* __restrict__ bUV,
        float* __restrict__ axs, float* __restrict__ ag, float* __restrict__ bjp,
        float* __restrict__ hw1y, float* __restrict__ hw2y,
        float* __restrict__ outp, float* __restrict__ outs){
    __shared__ SMem sm;
    const int blk = blockIdx.x, tid = threadIdx.x;

    // ---------- Phase A: edge scatter (128 edges/block) + weight premultiply ----------
    if (tid < 128){
        int e = (blk << 7) + tid;
        int s = ei[e], d = ei[N_EDGES + e];
        float wv = ew[e];
        atomicAdd(&deg[d], wv);
        int pos = atomicAdd(&cnt[d], 1);
        if (pos < CAP){
            float2 v;
            v.x = __int_as_float(s);
            v.y = wv;
            cedge[(d << 7) + pos] = v;
        }
    }
    if (blk == 509 || blk == 510){
        const float* Wc = (blk == 509) ? Wcz : Wch;
        const float* Wl = (blk == 509) ? Wlz : Wlh;
        float* Wp = (blk == 509) ? Wzp : Whp;
        for (int idx = tid; idx < IN_F*HID; idx += 512){
            int i = idx >> 6, f = idx & 63;
            float s = 0.f;
            #pragma unroll 8
            for (int k = 0; k < HID; ++k) s += Wc[i*HID+k] * Wl[k*HID+f];
            Wp[idx] = s;
        }
    } else if (blk == 511 && tid < 128){
        int which = tid >> 6, f = tid & 63;
        const float* Wl = which ? Wlh : Wlz;
        const float* bc = which ? bch : bcz;
        const float* bl = which ? blh : blz;
        float s = bl[f];
        for (int k = 0; k < HID; ++k) s += bc[k] * Wl[k*HID+f];
        bUV[which*HID + f] = s;
    }
    gbar(bar, 1*NBLK, blk);

    // ---------- Phase B: gather -> axs (4 nodes/block serial; R6 40x8 shape, padded part) ----------
    for (int rep = 0; rep < 4; ++rep){
        int n = (blk << 2) + rep;
        int slot = tid >> 3, fl = tid & 7;
        int m = min(cnt[n], CAP);
        if (slot < 40){
            const float4* X4 = (const float4*)x;
            float4 a0={0,0,0,0}, a1={0,0,0,0}, a2={0,0,0,0}, a3={0,0,0,0}, a4={0,0,0,0};
            for (int p = slot; p < m; p += 40){
                float2 ed = cedge[(n << 7) + p];
                int s = __float_as_int(ed.x);
                float c = ed.y * (1.f / sqrtf(deg[s] + 1.f));
                float4 x0 = X4[(0*N_NODES + s)*8 + fl];
                float4 x1 = X4[(1*N_NODES + s)*8 + fl];
                float4 x2 = X4[(2*N_NODES + s)*8 + fl];
                float4 x3 = X4[(3*N_NODES + s)*8 + fl];
                float4 x4v= X4[(4*N_NODES + s)*8 + fl];
                a0.x += c*x0.x; a0.y += c*x0.y; a0.z += c*x0.z; a0.w += c*x0.w;
                a1.x += c*x1.x; a1.y += c*x1.y; a1.z += c*x1.z; a1.w += c*x1.w;
                a2.x += c*x2.x; a2.y += c*x2.y; a2.z += c*x2.z; a2.w += c*x2.w;
                a3.x += c*x3.x; a3.y += c*x3.y; a3.z += c*x3.z; a3.w += c*x3.w;
                a4.x += c*x4v.x; a4.y += c*x4v.y; a4.z += c*x4v.z; a4.w += c*x4v.w;
            }
            *(float4*)&sm.ga.part[(slot*SEQL + 0)*PSTR + fl*4] = a0;
            *(float4*)&sm.ga.part[(slot*SEQL + 1)*PSTR + fl*4] = a1;
            *(float4*)&sm.ga.part[(slot*SEQL + 2)*PSTR + fl*4] = a2;
            *(float4*)&sm.ga.part[(slot*SEQL + 3)*PSTR + fl*4] = a3;
            *(float4*)&sm.ga.part[(slot*SEQL + 4)*PSTR + fl*4] = a4;
        }
        __syncthreads();
        if (tid < SEQL*IN_F){
            int tt = tid >> 5, ff = tid & 31;
            float dvn = 1.f / sqrtf(deg[n] + 1.f);
            float ps = 0.f;
            #pragma unroll 8
            for (int sl = 0; sl < 40; ++sl) ps += sm.ga.part[(sl*SEQL + tt)*PSTR + ff];
            axs[n*(SEQL*IN_F) + tid] = dvn*dvn * x[(tt*N_NODES + n)*IN_F + ff] + dvn * ps;
        }
        __syncthreads();
    }
    gbar(bar, 2*NBLK, blk);

    // ---------- Phase C: dense (blocks 0-255, wave-per-node, LDS-staged weights; R6 verbatim) ----------
    if (blk < 256){
        int w = tid >> 6, l = tid & 63;
        int n = (blk << 3) + w;
        sm.de.axsf[w*160 + l]      = axs[n*160 + l];
        sm.de.axsf[w*160 + 64 + l] = axs[n*160 + 64 + l];
        if (l < 32) sm.de.axsf[w*160 + 128 + l] = axs[n*160 + 128 + l];
        for (int idx = tid; idx < 2048; idx += 512){
            sm.de.wl[idx]        = Wzp[idx];
            sm.de.wl[2048 + idx] = Whp[idx];
        }
        __syncthreads();
        float bz = bUV[l], bh = bUV[HID + l];
        #pragma unroll
        for (int t = 0; t < SEQL; ++t){
            float zz = bz, hh = bh;
            #pragma unroll 8
            for (int i = 0; i < IN_F; ++i){
                float a = sm.de.axsf[w*160 + t*32 + i];
                zz += a * sm.de.wl[i*HID + l];
                hh += a * sm.de.wl[2048 + i*HID + l];
            }
            float z = 1.f / (1.f + expf(-zz));
            sm.de.hsf[w*320 + t*64 + l] = (1.f - z) * tanhf(hh);
        }
        float hr = bred[l];
        for (int t = 0; t < SEQL; ++t){
            __syncthreads();
            for (int idx = tid; idx < 4096; idx += 512) sm.de.wl[idx] = Wred[t*4096 + idx];
            __syncthreads();
            #pragma unroll 8
            for (int k = 0; k < HID; ++k)
                hr += sm.de.hsf[w*320 + t*64 + k] * sm.de.wl[k*HID + l];
        }
        sm.de.hembf[w*HID + l] = hr;
        float rA, rB, rC;
        #pragma unroll
        for (int o = 0; o < 3; ++o){
            __syncthreads();
            const float* W = (o == 0) ? Wi1 : (o == 1) ? (Wi1 + HID*HID) : Wc1;
            for (int idx = tid; idx < 4096; idx += 512) sm.de.wl[idx] = W[idx];
            __syncthreads();
            float acc = (o == 1) ? bi1[l] : 0.f;
            #pragma unroll 8
            for (int k = 0; k < HID; ++k) acc += sm.de.hembf[w*HID + k] * sm.de.wl[k*HID + l];
            if (o == 0) rA = acc; else if (o == 1) rB = acc; else rC = acc;
        }
        ag  [n*HID + l] = rA;
        bjp [n*HID + l] = rB;                    // bi1 folded in
        hw1y[n*HID + l] = rC * (1.f / sqrtf(deg[n] + 1.f));
    }
    gbar(bar, 3*NBLK, blk);

    // ---------- Phase D: gcn1 (blocks 0-255) | score tiles 0-511 ----------
    if (blk < 256){
        int w = tid >> 6, l = tid & 63;
        gcn1_node((blk << 3) + w, l, deg, cnt, cedge, hw1y, bc1, g1, be1, Wc2, hw2y);
    } else {
        score_tile((blk - 256)*2,     tid, sm, ag, bjp, Wi2, bi2, outs);
        score_tile((blk - 256)*2 + 1, tid, sm, ag, bjp, Wi2, bi2, outs);
    }
    gbar(bar, 4*NBLK, blk);

    // ---------- Phase E: gcn2+outp (blocks 0-255) | score tiles 512-1023 ----------
    if (blk < 256){
        int w = tid >> 6, l = tid & 63;
        gcn2_node((blk << 3) + w, l, deg, cnt, cedge, hw2y, bc2, g2, be2, Wout, bout, outp);
    } else {
        score_tile(512 + (blk - 256)*2,     tid, sm, ag, bjp, Wi2, bi2, outs);
        score_tile(512 + (blk - 256)*2 + 1, tid, sm, ag, bjp, Wi2, bi2, outs);
    }

    // ---------- Phase F: score tiles 1024-2047 (no barrier needed) ----------
    score_tile(1024 + blk*2,     tid, sm, ag, bjp, Wi2, bi2, outs);
    score_tile(1024 + blk*2 + 1, tid, sm, ag, bjp, Wi2, bi2, outs);
}

extern "C" void kernel_launch(void* const* d_in, const int* in_sizes, int n_in,
                              void* d_out, int out_size, void* d_ws, size_t ws_size,
                              hipStream_t stream){
    const float* x   = (const float*)d_in[0];
    const float* ew  = (const float*)d_in[1];
    const float* Wcz = (const float*)d_in[2];  const float* bcz = (const float*)d_in[3];
    const float* Wlz = (const float*)d_in[4];  const float* blz = (const float*)d_in[5];
    // d_in[6..9]: Wcr/bcr/Wlr/blr — dead code (H=0 so reset gate has no effect)
    const float* Wch = (const float*)d_in[10]; const float* bch = (const float*)d_in[11];
    const float* Wlh = (const float*)d_in[12]; const float* blh = (const float*)d_in[13];
    const float* Wred= (const float*)d_in[14]; const float* bred= (const float*)d_in[15];
    const float* Wc1 = (const float*)d_in[16]; const float* bc1 = (const float*)d_in[17];
    const float* Wc2 = (const float*)d_in[18]; const float* bc2 = (const float*)d_in[19];
    const float* g1  = (const float*)d_in[20]; const float* be1 = (const float*)d_in[21];
    const float* g2  = (const float*)d_in[22]; const float* be2 = (const float*)d_in[23];
    const float* Wout= (const float*)d_in[24]; const float* bout= (const float*)d_in[25];
    const float* Wi1 = (const float*)d_in[26]; const float* bi1 = (const float*)d_in[27];
    const float* Wi2 = (const float*)d_in[28]; const float* bi2 = (const float*)d_in[29];
    const int*  ei  = (const int*)d_in[30];

    float* w = (float*)d_ws;              // float offsets, 16B aligned
    float* deg   = w;                     // 2048 floats
    int*   cnt   = (int*)(w + 2048);      // 2048 ints
    unsigned* bar= (unsigned*)(w + 4096); // 16 counters
    float2* cedge= (float2*)(w + 4112);   // 2048*128 pairs = 524288 floats
    float* Wzp   = w + 528400;            // 2048
    float* Whp   = w + 530448;            // 2048
    float* bUV   = w + 532496;            // 128
    float* ag    = w + 532624;            // 131072
    float* bjp   = w + 663696;            // 131072
    float* hw1y  = w + 794768;            // 131072  (= dinv * emb@Wc1)
    float* hw2y  = w + 925840;            // 131072  (= dinv * hsh@Wc2)
    float* axs   = w + 1056912;           // 2048*160 = 327680
    float* outp  = (float*)d_out;
    float* outs  = (float*)d_out + N_NODES*OUT_F;

    hipMemsetAsync(deg, 0, 16448, stream);   // deg + cnt + bar
    k_mega<<<NBLK, 512, 0, stream>>>(x, ew, ei,
        Wcz, Wlz, bcz, blz, Wch, Wlh, bch, blh, Wred, bred,
        Wc1, bc1, Wc2, bc2, g1, be1, g2, be2, Wout, bout, Wi1, bi1, Wi2, bi2,
        deg, cnt, bar, cedge, Wzp, Whp, bUV, axs, ag, bjp, hw1y, hw2y, outp, outs);
}

// Round 8
// 196.138 us; speedup vs baseline: 2.3656x; 2.3656x over previous
//
#include <hip/hip_runtime.h>
#include <math.h>

#define N_NODES 2048
#define N_EDGES 65536
#define SEQL 5
#define IN_F 32
#define HID 64
#define OUT_F 16
#define LN_EPS 1e-5f
#define CAP 128   // fixed slot capacity per node; in-degree ~ Poisson(32), P(>128) ~ e^-200

// ===== K1: edge slot-scatter (1 int + 1 float atomic per edge) + weight premultiply =====
__global__ __launch_bounds__(256) void k_build(
        const int* __restrict__ ei, const float* __restrict__ ew,
        const float* __restrict__ Wcz, const float* __restrict__ Wlz,
        const float* __restrict__ bcz, const float* __restrict__ blz,
        const float* __restrict__ Wch, const float* __restrict__ Wlh,
        const float* __restrict__ bch, const float* __restrict__ blh,
        float* __restrict__ deg, int* __restrict__ cnt, float2* __restrict__ cedge,
        float* __restrict__ Wzp, float* __restrict__ Whp, float* __restrict__ bUV){
    int b = blockIdx.x, t = threadIdx.x;
    if (b < 256){
        int e = b * 256 + t;
        int s = ei[e], d = ei[N_EDGES + e];
        float wv = ew[e];
        atomicAdd(&deg[d], wv);
        int pos = atomicAdd(&cnt[d], 1);
        if (pos < CAP){
            float2 v;
            v.x = __int_as_float(s);
            v.y = wv;                          // raw weight; dinv folded at gather time
            cedge[(d << 7) + pos] = v;
        }
    } else {
        const float* Wc = (b == 256) ? Wcz : Wch;
        const float* Wl = (b == 256) ? Wlz : Wlh;
        const float* bc = (b == 256) ? bcz : bch;
        const float* bl = (b == 256) ? blz : blh;
        float* Wp = (b == 256) ? Wzp : Whp;
        for (int idx = t; idx < IN_F*HID; idx += 256){
            int i = idx >> 6, f = idx & 63;
            float s = 0.f;
            #pragma unroll 8
            for (int k = 0; k < HID; ++k) s += Wc[i*HID+k] * Wl[k*HID+f];
            Wp[idx] = s;
        }
        if (t < HID){
            float s = bl[t];
            for (int k = 0; k < HID; ++k) s += bc[k] * Wl[k*HID+t];
            bUV[(b-256)*HID + t] = s;
        }
    }
}

// ===== K2a: gather only (block-per-node, 40 slots x 8 f4-lanes) -> axs to global =====
__global__ __launch_bounds__(320) void k_gather(const float* __restrict__ x,
        const float* __restrict__ deg, const int* __restrict__ cnt,
        const float2* __restrict__ cedge, float* __restrict__ axs_out){
    int n = blockIdx.x;
    int tid = threadIdx.x;
    __shared__ float part[40*SEQL*IN_F];       // 25.6 KB
    const int slot = tid >> 3, fl = tid & 7;   // 40 slots x 8 lanes (float4 each)
    int m = min(cnt[n], CAP);
    const float4* X4 = (const float4*)x;
    float4 a0 = {0,0,0,0}, a1 = {0,0,0,0}, a2 = {0,0,0,0}, a3 = {0,0,0,0}, a4 = {0,0,0,0};
    for (int p = slot; p < m; p += 40){
        float2 ed = cedge[(n << 7) + p];
        int s = __float_as_int(ed.x);
        float c = ed.y * (1.f / sqrtf(deg[s] + 1.f));   // deg is L1/L2-resident (8 KB)
        float4 x0 = X4[(0*N_NODES + s)*8 + fl];
        float4 x1 = X4[(1*N_NODES + s)*8 + fl];
        float4 x2 = X4[(2*N_NODES + s)*8 + fl];
        float4 x3 = X4[(3*N_NODES + s)*8 + fl];
        float4 x4v= X4[(4*N_NODES + s)*8 + fl];
        a0.x += c*x0.x; a0.y += c*x0.y; a0.z += c*x0.z; a0.w += c*x0.w;
        a1.x += c*x1.x; a1.y += c*x1.y; a1.z += c*x1.z; a1.w += c*x1.w;
        a2.x += c*x2.x; a2.y += c*x2.y; a2.z += c*x2.z; a2.w += c*x2.w;
        a3.x += c*x3.x; a3.y += c*x3.y; a3.z += c*x3.z; a3.w += c*x3.w;
        a4.x += c*x4v.x; a4.y += c*x4v.y; a4.z += c*x4v.z; a4.w += c*x4v.w;
    }
    *(float4*)&part[(slot*SEQL + 0)*IN_F + fl*4] = a0;
    *(float4*)&part[(slot*SEQL + 1)*IN_F + fl*4] = a1;
    *(float4*)&part[(slot*SEQL + 2)*IN_F + fl*4] = a2;
    *(float4*)&part[(slot*SEQL + 3)*IN_F + fl*4] = a3;
    *(float4*)&part[(slot*SEQL + 4)*IN_F + fl*4] = a4;
    __syncthreads();
    if (tid < SEQL*IN_F){
        int tt = tid >> 5, ff = tid & 31;
        float dvn = 1.f / sqrtf(deg[n] + 1.f);
        float ps = 0.f;
        #pragma unroll 8
        for (int sl = 0; sl < 40; ++sl) ps += part[(sl*SEQL + tt)*IN_F + ff];
        axs_out[n*(SEQL*IN_F) + tid] = dvn*dvn * x[(tt*N_NODES + n)*IN_F + ff] + dvn * ps;
    }
}

// ===== K2b: dense phases, 8 nodes/block (wave-per-node), weights staged via 16KB LDS =====
__global__ __launch_bounds__(512) void k_dense(const float* __restrict__ axs_in,
        const float* __restrict__ deg,
        const float* __restrict__ Wzp, const float* __restrict__ Whp,
        const float* __restrict__ bUV,
        const float* __restrict__ Wred, const float* __restrict__ bred,
        const float* __restrict__ Wi1, const float* __restrict__ bi1,
        const float* __restrict__ Wc1,
        float* __restrict__ ag, float* __restrict__ bjp, float* __restrict__ hw1y){
    __shared__ float wl[4096];                 // 16 KB weight slice
    __shared__ float axsf[8*SEQL*IN_F];        // 5 KB
    __shared__ float hsf[8*SEQL*HID];          // 10 KB
    __shared__ float hembf[8*HID];             // 2 KB
    int tid = threadIdx.x;
    int w = tid >> 6, l = tid & 63;
    int n = (blockIdx.x << 3) + w;
    // wave-local axs load (160 floats per node; no cross-wave readers)
    axsf[w*160 + l]      = axs_in[n*160 + l];
    axsf[w*160 + 64 + l] = axs_in[n*160 + 64 + l];
    if (l < 32) axsf[w*160 + 128 + l] = axs_in[n*160 + 128 + l];
    // stage gate weights: wl[0..2047]=Wzp, wl[2048..4095]=Whp
    for (int idx = tid; idx < 2048; idx += 512){
        wl[idx]        = Wzp[idx];
        wl[2048 + idx] = Whp[idx];
    }
    __syncthreads();
    // ---- gate: hs[t][l] for this wave's node ----
    float bz = bUV[l], bh = bUV[HID + l];
    #pragma unroll
    for (int t = 0; t < SEQL; ++t){
        float zz = bz, hh = bh;
        #pragma unroll 8
        for (int i = 0; i < IN_F; ++i){
            float a = axsf[w*160 + t*32 + i];  // wave-uniform LDS broadcast
            zz += a * wl[i*HID + l];
            hh += a * wl[2048 + i*HID + l];
        }
        float z = 1.f / (1.f + expf(-zz));
        hsf[w*320 + t*64 + l] = (1.f - z) * tanhf(hh);
    }
    // ---- Wred in 5 staged 16KB slices: hemb = bred + sum_t sum_k hs[t][k]*Wred[t*64+k][l] ----
    float hr = bred[l];
    for (int t = 0; t < SEQL; ++t){
        __syncthreads();                       // previous slice's readers done
        for (int idx = tid; idx < 4096; idx += 512) wl[idx] = Wred[t*4096 + idx];
        __syncthreads();
        #pragma unroll 8
        for (int k = 0; k < HID; ++k)
            hr += hsf[w*320 + t*64 + k] * wl[k*HID + l];
    }
    hembf[w*HID + l] = hr;                     // same-wave producer/consumer
    // ---- 3 matvecs in staged slices: ag, bjp(+bi1), hw1y(=dinv*emb@Wc1) ----
    float rA, rB, rC;
    #pragma unroll
    for (int o = 0; o < 3; ++o){
        __syncthreads();
        const float* W = (o == 0) ? Wi1 : (o == 1) ? (Wi1 + HID*HID) : Wc1;
        for (int idx = tid; idx < 4096; idx += 512) wl[idx] = W[idx];
        __syncthreads();
        float acc = (o == 1) ? bi1[l] : 0.f;
        #pragma unroll 8
        for (int k = 0; k < HID; ++k) acc += hembf[w*HID + k] * wl[k*HID + l];
        if (o == 0) rA = acc; else if (o == 1) rB = acc; else rC = acc;
    }
    ag  [n*HID + l] = rA;
    bjp [n*HID + l] = rB;                      // bi1 folded in
    hw1y[n*HID + l] = rC * (1.f / sqrtf(deg[n] + 1.f));
}

// ===== K3: gcn1 wave-per-node (blocks 0..255) + score tiles 0..1023 =====
__global__ __launch_bounds__(512) void k_gcn1s(
        const float* __restrict__ hw1y, const float* __restrict__ deg,
        const int* __restrict__ cnt, const float2* __restrict__ cedge,
        const float* __restrict__ bc1, const float* __restrict__ g1, const float* __restrict__ be1,
        const float* __restrict__ Wc2, float* __restrict__ hw2y,
        const float* __restrict__ ag, const float* __restrict__ bjp,
        const float* __restrict__ Wi2, const float* __restrict__ bi2,
        float* __restrict__ outs){
    int blk = blockIdx.x;
    int tid = threadIdx.x;
    if (blk < 256){
        // ---- wave-per-node: no __syncthreads, no LDS in this path ----
        int w = tid >> 6, l = tid & 63;
        int n = (blk << 3) + w;
        int slot = l >> 4, fl = l & 15;
        int m = min(cnt[n], CAP);
        float dv = 1.f / sqrtf(deg[n] + 1.f);
        const float4* H4 = (const float4*)hw1y;
        float4 acc = {0.f,0.f,0.f,0.f};
        if (slot == 0) acc = H4[n*16 + fl];    // self term (hw1y pre-scaled by dinv[n])
        for (int p = slot; p < m; p += 4){
            float2 ed = cedge[(n << 7) + p];
            int s = __float_as_int(ed.x); float c = ed.y;   // hw1y pre-scaled by dinv[s]
            float4 h = H4[s*16 + fl];
            acc.x += c*h.x; acc.y += c*h.y; acc.z += c*h.z; acc.w += c*h.w;
        }
        acc.x += __shfl_xor(acc.x, 16); acc.y += __shfl_xor(acc.y, 16);
        acc.z += __shfl_xor(acc.z, 16); acc.w += __shfl_xor(acc.w, 16);
        acc.x += __shfl_xor(acc.x, 32); acc.y += __shfl_xor(acc.y, 32);
        acc.z += __shfl_xor(acc.z, 32); acc.w += __shfl_xor(acc.w, 32);
        float4 b4 = ((const float4*)bc1)[fl];
        float4 g;
        g.x = b4.x + dv*acc.x; g.y = b4.y + dv*acc.y;
        g.z = b4.z + dv*acc.z; g.w = b4.w + dv*acc.w;
        float s4 = g.x + g.y + g.z + g.w;
        s4 += __shfl_xor(s4, 1); s4 += __shfl_xor(s4, 2);
        s4 += __shfl_xor(s4, 4); s4 += __shfl_xor(s4, 8);
        float mu = s4 * (1.f/64.f);
        float4 d;
        d.x = g.x - mu; d.y = g.y - mu; d.z = g.z - mu; d.w = g.w - mu;
        float v4 = d.x*d.x + d.y*d.y + d.z*d.z + d.w*d.w;
        v4 += __shfl_xor(v4, 1); v4 += __shfl_xor(v4, 2);
        v4 += __shfl_xor(v4, 4); v4 += __shfl_xor(v4, 8);
        float rs = 1.f / sqrtf(v4 * (1.f/64.f) + LN_EPS);
        float4 gm = ((const float4*)g1)[fl], be = ((const float4*)be1)[fl];
        float4 h4;
        h4.x = fmaxf(d.x*rs*gm.x + be.x, 0.f);
        h4.y = fmaxf(d.y*rs*gm.y + be.y, 0.f);
        h4.z = fmaxf(d.z*rs*gm.z + be.z, 0.f);
        h4.w = fmaxf(d.w*rs*gm.w + be.w, 0.f);
        float o = 0.f;
        #pragma unroll 4
        for (int gk = 0; gk < 16; ++gk){
            float hb0 = __shfl(h4.x, gk);
            float hb1 = __shfl(h4.y, gk);
            float hb2 = __shfl(h4.z, gk);
            float hb3 = __shfl(h4.w, gk);
            o += hb0 * Wc2[(4*gk+0)*HID + l];
            o += hb1 * Wc2[(4*gk+1)*HID + l];
            o += hb2 * Wc2[(4*gk+2)*HID + l];
            o += hb3 * Wc2[(4*gk+3)*HID + l];
        }
        hw2y[n*HID + l] = dv * o;              // pre-scale for gcn2 gather
    } else {
        __shared__ float bs[64*65];            // score branch only
        __shared__ float wv[64];
        int tl = blk - 256;                    // tiles 0..1023
        int j0 = (tl & 31) * 64;
        int i0 = (tl >> 5) * 32;
        for (int idx = tid; idx < 4096; idx += 512){
            int jj = idx >> 6, f = idx & 63;
            bs[jj*65 + f] = bjp[(j0 + jj)*HID + f];
        }
        if (tid < 64) wv[tid] = Wi2[tid];
        __syncthreads();
        int tj = tid & 63;
        int w = __builtin_amdgcn_readfirstlane(tid >> 6);   // wave-uniform -> scalar a-loads
        const float* ar = ag + (i0 + w*4)*HID;
        float bi2v = bi2[0];
        float acc0 = 0.f, acc1 = 0.f, acc2 = 0.f, acc3 = 0.f;
        #pragma unroll
        for (int f = 0; f < 64; ++f){
            float bv = bs[tj*65 + f];
            float wf = wv[f];
            acc0 += fmaxf(ar[       f] + bv, 0.f) * wf;
            acc1 += fmaxf(ar[ 64 +  f] + bv, 0.f) * wf;
            acc2 += fmaxf(ar[128 +  f] + bv, 0.f) * wf;
            acc3 += fmaxf(ar[192 +  f] + bv, 0.f) * wf;
        }
        long ro = (long)(i0 + w*4) * N_NODES + j0 + tj;
        outs[ro                ] = acc0 + bi2v;
        outs[ro +     N_NODES  ] = acc1 + bi2v;
        outs[ro + 2L* N_NODES  ] = acc2 + bi2v;
        outs[ro + 3L* N_NODES  ] = acc3 + bi2v;
    }
}

// ===== K4: gcn2 wave-per-node + outp (blocks 0..255) + score tiles 1024..2047 =====
__global__ __launch_bounds__(512) void k_gcn2s(
        const float* __restrict__ hw2y, const float* __restrict__ deg,
        const int* __restrict__ cnt, const float2* __restrict__ cedge,
        const float* __restrict__ bc2, const float* __restrict__ g2, const float* __restrict__ be2,
        const float* __restrict__ Wout, const float* __restrict__ bout,
        const float* __restrict__ ag, const float* __restrict__ bjp,
        const float* __restrict__ Wi2, const float* __restrict__ bi2,
        float* __restrict__ outp, float* __restrict__ outs){
    int blk = blockIdx.x;
    int tid = threadIdx.x;
    if (blk < 256){
        int w = tid >> 6, l = tid & 63;
        int n = (blk << 3) + w;
        int slot = l >> 4, fl = l & 15;
        int m = min(cnt[n], CAP);
        float dv = 1.f / sqrtf(deg[n] + 1.f);
        const float4* H4 = (const float4*)hw2y;
        float4 acc = {0.f,0.f,0.f,0.f};
        if (slot == 0) acc = H4[n*16 + fl];
        for (int p = slot; p < m; p += 4){
            float2 ed = cedge[(n << 7) + p];
            int s = __float_as_int(ed.x); float c = ed.y;
            float4 h = H4[s*16 + fl];
            acc.x += c*h.x; acc.y += c*h.y; acc.z += c*h.z; acc.w += c*h.w;
        }
        acc.x += __shfl_xor(acc.x, 16); acc.y += __shfl_xor(acc.y, 16);
        acc.z += __shfl_xor(acc.z, 16); acc.w += __shfl_xor(acc.w, 16);
        acc.x += __shfl_xor(acc.x, 32); acc.y += __shfl_xor(acc.y, 32);
        acc.z += __shfl_xor(acc.z, 32); acc.w += __shfl_xor(acc.w, 32);
        float4 b4 = ((const float4*)bc2)[fl];
        float4 g;
        g.x = b4.x + dv*acc.x; g.y = b4.y + dv*acc.y;
        g.z = b4.z + dv*acc.z; g.w = b4.w + dv*acc.w;
        float s4 = g.x + g.y + g.z + g.w;
        s4 += __shfl_xor(s4, 1); s4 += __shfl_xor(s4, 2);
        s4 += __shfl_xor(s4, 4); s4 += __shfl_xor(s4, 8);
        float mu = s4 * (1.f/64.f);
        float4 d;
        d.x = g.x - mu; d.y = g.y - mu; d.z = g.z - mu; d.w = g.w - mu;
        float v4 = d.x*d.x + d.y*d.y + d.z*d.z + d.w*d.w;
        v4 += __shfl_xor(v4, 1); v4 += __shfl_xor(v4, 2);
        v4 += __shfl_xor(v4, 4); v4 += __shfl_xor(v4, 8);
        float rs = 1.f / sqrtf(v4 * (1.f/64.f) + LN_EPS);
        float4 gm = ((const float4*)g2)[fl], be = ((const float4*)be2)[fl];
        float4 h4;
        h4.x = fmaxf(d.x*rs*gm.x + be.x, 0.f);
        h4.y = fmaxf(d.y*rs*gm.y + be.y, 0.f);
        h4.z = fmaxf(d.z*rs*gm.z + be.z, 0.f);
        h4.w = fmaxf(d.w*rs*gm.w + be.w, 0.f);
        int f2 = l & 15;
        float o = bout[f2];
        #pragma unroll 4
        for (int gk = 0; gk < 16; ++gk){
            float hb0 = __shfl(h4.x, gk);
            float hb1 = __shfl(h4.y, gk);
            float hb2 = __shfl(h4.z, gk);
            float hb3 = __shfl(h4.w, gk);
            o += hb0 * Wout[(4*gk+0)*OUT_F + f2];
            o += hb1 * Wout[(4*gk+1)*OUT_F + f2];
            o += hb2 * Wout[(4*gk+2)*OUT_F + f2];
            o += hb3 * Wout[(4*gk+3)*OUT_F + f2];
        }
        if (slot == 0) outp[n*OUT_F + f2] = o;
    } else {
        __shared__ float bs[64*65];
        __shared__ float wv[64];
        int tl = blk - 256 + 1024;             // tiles 1024..2047
        int j0 = (tl & 31) * 64;
        int i0 = (tl >> 5) * 32;
        for (int idx = tid; idx < 4096; idx += 512){
            int jj = idx >> 6, f = idx & 63;
            bs[jj*65 + f] = bjp[(j0 + jj)*HID + f];
        }
        if (tid < 64) wv[tid] = Wi2[tid];
        __syncthreads();
        int tj = tid & 63;
        int w = __builtin_amdgcn_readfirstlane(tid >> 6);
        const float* ar = ag + (i0 + w*4)*HID;
        float bi2v = bi2[0];
        float acc0 = 0.f, acc1 = 0.f, acc2 = 0.f, acc3 = 0.f;
        #pragma unroll
        for (int f = 0; f < 64; ++f){
            float bv = bs[tj*65 + f];
            float wf = wv[f];
            acc0 += fmaxf(ar[       f] + bv, 0.f) * wf;
            acc1 += fmaxf(ar[ 64 +  f] + bv, 0.f) * wf;
            acc2 += fmaxf(ar[128 +  f] + bv, 0.f) * wf;
            acc3 += fmaxf(ar[192 +  f] + bv, 0.f) * wf;
        }
        long ro = (long)(i0 + w*4) * N_NODES + j0 + tj;
        outs[ro                ] = acc0 + bi2v;
        outs[ro +     N_NODES  ] = acc1 + bi2v;
        outs[ro + 2L* N_NODES  ] = acc2 + bi2v;
        outs[ro + 3L* N_NODES  ] = acc3 + bi2v;
    }
}

extern "C" void kernel_launch(void* const* d_in, const int* in_sizes, int n_in,
                              void* d_out, int out_size, void* d_ws, size_t ws_size,
                              hipStream_t stream){
    const float* x   = (const float*)d_in[0];
    const float* ew  = (const float*)d_in[1];
    const float* Wcz = (const float*)d_in[2];  const float* bcz = (const float*)d_in[3];
    const float* Wlz = (const float*)d_in[4];  const float* blz = (const float*)d_in[5];
    // d_in[6..9]: Wcr/bcr/Wlr/blr — dead code (H=0 so reset gate has no effect)
    const float* Wch = (const float*)d_in[10]; const float* bch = (const float*)d_in[11];
    const float* Wlh = (const float*)d_in[12]; const float* blh = (const float*)d_in[13];
    const float* Wred= (const float*)d_in[14]; const float* bred= (const float*)d_in[15];
    const float* Wc1 = (const float*)d_in[16]; const float* bc1 = (const float*)d_in[17];
    const float* Wc2 = (const float*)d_in[18]; const float* bc2 = (const float*)d_in[19];
    const float* g1  = (const float*)d_in[20]; const float* be1 = (const float*)d_in[21];
    const float* g2  = (const float*)d_in[22]; const float* be2 = (const float*)d_in[23];
    const float* Wout= (const float*)d_in[24]; const float* bout= (const float*)d_in[25];
    const float* Wi1 = (const float*)d_in[26]; const float* bi1 = (const float*)d_in[27];
    const float* Wi2 = (const float*)d_in[28]; const float* bi2 = (const float*)d_in[29];
    const int*  ei  = (const int*)d_in[30];

    float* w = (float*)d_ws;              // float offsets, 16B aligned
    float* deg   = w;                     // 2048 floats   [memset 16 KB covers deg+cnt]
    int*   cnt   = (int*)(w + 2048);      // 2048 ints
    float2* cedge= (float2*)(w + 4096);   // 2048*128 pairs = 524288 floats [4096, 528384)
    float* Wzp   = w + 528384;            // 2048
    float* Whp   = w + 530432;            // 2048
    float* bUV   = w + 532480;            // 128
    float* ag    = w + 532608;            // 131072
    float* bjp   = w + 663680;            // 131072
    float* hw1y  = w + 794752;            // 131072  (= dinv * emb@Wc1)
    float* hw2y  = w + 925824;            // 131072  (= dinv * hsh@Wc2)
    float* axs   = w + 1056896;           // 2048*160 = 327680

    hipMemsetAsync(deg, 0, 16384, stream);
    k_build<<<258, 256, 0, stream>>>(ei, ew, Wcz, Wlz, bcz, blz, Wch, Wlh, bch, blh,
                                     deg, cnt, cedge, Wzp, Whp, bUV);
    k_gather<<<N_NODES, 320, 0, stream>>>(x, deg, cnt, cedge, axs);
    k_dense<<<256, 512, 0, stream>>>(axs, deg, Wzp, Whp, bUV, Wred, bred,
                                     Wi1, bi1, Wc1, ag, bjp, hw1y);
    k_gcn1s<<<256 + 1024, 512, 0, stream>>>(hw1y, deg, cnt, cedge, bc1, g1, be1,
                                            Wc2, hw2y, ag, bjp, Wi2, bi2,
                                            (float*)d_out + N_NODES*OUT_F);
    k_gcn2s<<<256 + 1024, 512, 0, stream>>>(hw2y, deg, cnt, cedge, bc2, g2, be2,
                                            Wout, bout, ag, bjp, Wi2, bi2,
                                            (float*)d_out, (float*)d_out + N_NODES*OUT_F);
}